// Round 15
// baseline (124.179 us; speedup 1.0000x reference)
//
#include <hip/hip_runtime.h>

#define NN 20000
#define EE 320000
#define TE 340000        // EE + NN self loops
#define NEG 0.2f
#define NB_SCORE 1329    // ceil(TE/256)
#define NB_GEMM 625      // 20000 / 32
#define CAP 96           // max bin capacity (deg ~ 1+Poisson(16); P(>95) ~ 1e-40)

typedef __attribute__((ext_vector_type(8))) _Float16 half8;
typedef __attribute__((ext_vector_type(4))) _Float16 half4v;
typedef __attribute__((ext_vector_type(4))) float f32x4;

__device__ __forceinline__ float lrelu(float v) { return v > 0.f ? v : NEG * v; }

// ---------------- W -> fp16 split tables in k-blocked layout: Wb[k>>3][col][k&7]; zero done ----------------
__global__ __launch_bounds__(256) void k_wsplit(const float* __restrict__ W,
                                                _Float16* __restrict__ Wh, _Float16* __restrict__ Wl,
                                                unsigned* __restrict__ done) {
    if (blockIdx.x == 0 && threadIdx.x == 0) *done = 0u;
    int c = blockIdx.x;      // 256 cols
    int k = threadIdx.x;     // 256 k
    float w = W[k * 256 + c];
    _Float16 hi = (_Float16)w;
    _Float16 lo = (_Float16)(w - (float)hi);
    int idx = (k >> 3) * 2048 + c * 8 + (k & 7);
    Wh[idx] = hi;
    Wl[idx] = lo;
}

// ---------------- MFMA GEMM: h16 = fp16(x @ W), Es/Ed = exp(alpha) directly ----------------
// 625 blocks x 256 thr (4 waves); 32 rows/block; wave = 2 row-tiles x 64 cols (= head wid).
__global__ __launch_bounds__(256, 4) void k_gemm(const float* __restrict__ x,
                                                 const _Float16* __restrict__ Wh,
                                                 const _Float16* __restrict__ Wl,
                                                 const float* __restrict__ att, _Float16* __restrict__ h16,
                                                 float* __restrict__ Es, float* __restrict__ Ed,
                                                 int* __restrict__ cnt) {
    __shared__ _Float16 xh[32][264];   // 16.5 KB
    __shared__ _Float16 xl[32][264];   // 16.5 KB
    const int tid = threadIdx.x;
    const int r0 = blockIdx.x * 32;

    if (tid < 32) cnt[r0 + tid] = 0;   // zero bin counters (cursors for k_fill)

    const float4* x4 = (const float4*)x;
    #pragma unroll
    for (int i = 0; i < 8; ++i) {
        int slot = tid + i * 256;      // 2048 float4 slots = 32 rows x 64
        int row = slot >> 6, c4 = slot & 63;
        float4 v = x4[(r0 + row) * 64 + c4];
        _Float16 h0 = (_Float16)v.x, h1 = (_Float16)v.y, h2 = (_Float16)v.z, h3 = (_Float16)v.w;
        half4v hv = {h0, h1, h2, h3};
        half4v lv = {(_Float16)(v.x - (float)h0), (_Float16)(v.y - (float)h1),
                     (_Float16)(v.z - (float)h2), (_Float16)(v.w - (float)h3)};
        *(half4v*)&xh[row][c4 * 4] = hv;
        *(half4v*)&xl[row][c4 * 4] = lv;
    }
    __syncthreads();

    const int lane = tid & 63, wid = tid >> 6;
    const int ch = wid;                         // col-quarter = head of this wave
    const int grp = lane >> 4, li = lane & 15;  // k-group / row-or-col index in fragment

    f32x4 acc[2][4];
    #pragma unroll
    for (int rt = 0; rt < 2; ++rt)
        #pragma unroll
        for (int i = 0; i < 4; ++i) acc[rt][i] = (f32x4){0.f, 0.f, 0.f, 0.f};

    const _Float16* bb_h = Wh + (ch * 64 + li) * 8 + grp * 2048;
    const _Float16* bb_l = Wl + (ch * 64 + li) * 8 + grp * 2048;

    for (int ks = 0; ks < 8; ++ks) {            // K = 8 steps of 32
        half8 ah0 = *(const half8*)&xh[li][ks * 32 + grp * 8];
        half8 al0 = *(const half8*)&xl[li][ks * 32 + grp * 8];
        half8 ah1 = *(const half8*)&xh[16 + li][ks * 32 + grp * 8];
        half8 al1 = *(const half8*)&xl[16 + li][ks * 32 + grp * 8];
        const _Float16* ph = bb_h + ks * 8192;
        const _Float16* pl = bb_l + ks * 8192;
        #pragma unroll
        for (int ct = 0; ct < 4; ++ct) {        // 4 col-tiles of 16; B reused for both row-tiles
            half8 bh = *(const half8*)(ph + ct * 128);
            half8 bl = *(const half8*)(pl + ct * 128);
            acc[0][ct] = __builtin_amdgcn_mfma_f32_16x16x32_f16(ah0, bh, acc[0][ct], 0, 0, 0);
            acc[0][ct] = __builtin_amdgcn_mfma_f32_16x16x32_f16(al0, bh, acc[0][ct], 0, 0, 0);
            acc[0][ct] = __builtin_amdgcn_mfma_f32_16x16x32_f16(ah0, bl, acc[0][ct], 0, 0, 0);
            acc[0][ct] = __builtin_amdgcn_mfma_f32_16x16x32_f16(al0, bl, acc[0][ct], 0, 0, 0);
            acc[1][ct] = __builtin_amdgcn_mfma_f32_16x16x32_f16(ah1, bh, acc[1][ct], 0, 0, 0);
            acc[1][ct] = __builtin_amdgcn_mfma_f32_16x16x32_f16(al1, bh, acc[1][ct], 0, 0, 0);
            acc[1][ct] = __builtin_amdgcn_mfma_f32_16x16x32_f16(ah1, bl, acc[1][ct], 0, 0, 0);
            acc[1][ct] = __builtin_amdgcn_mfma_f32_16x16x32_f16(al1, bl, acc[1][ct], 0, 0, 0);
        }
    }

    // epilogue: h16 store + alpha partials -> Es/Ed = exp(alpha) directly.
    float pss[2][4] = {{0.f,0.f,0.f,0.f},{0.f,0.f,0.f,0.f}};
    float psd[2][4] = {{0.f,0.f,0.f,0.f},{0.f,0.f,0.f,0.f}};
    #pragma unroll
    for (int rt = 0; rt < 2; ++rt) {
        #pragma unroll
        for (int ct = 0; ct < 4; ++ct) {
            int cl = ct * 16 + li;                   // col within head, 0..63
            float avc = att[ch * 128 + cl];          // a_src coef
            float dvc = att[ch * 128 + 64 + cl];     // a_dst coef
            #pragma unroll
            for (int reg = 0; reg < 4; ++reg) {
                float v = acc[rt][ct][reg];
                h16[(r0 + rt * 16 + grp * 4 + reg) * 256 + ch * 64 + cl] = (_Float16)v;
                float l = lrelu(v);
                pss[rt][reg] += l * avc;
                psd[rt][reg] += l * dvc;
            }
        }
    }
    #pragma unroll
    for (int rt = 0; rt < 2; ++rt)
        #pragma unroll
        for (int reg = 0; reg < 4; ++reg) {
            #pragma unroll
            for (int m = 1; m < 16; m <<= 1) {
                pss[rt][reg] += __shfl_xor(pss[rt][reg], m, 64);
                psd[rt][reg] += __shfl_xor(psd[rt][reg], m, 64);
            }
        }
    if (li == 0) {
        #pragma unroll
        for (int rt = 0; rt < 2; ++rt)
            #pragma unroll
            for (int reg = 0; reg < 4; ++reg) {
                int row = r0 + rt * 16 + grp * 4 + reg;
                Es[row * 4 + ch] = expf(pss[rt][reg]);
                Ed[row * 4 + ch] = expf(psd[rt][reg]);
            }
    }
}

// ---------------- fill: u16 bucket scatter + Z partials + last-block combine -> invZ ----------------
__global__ __launch_bounds__(256) void k_fill(const int* __restrict__ es, const int* __restrict__ ed,
                                              const float* __restrict__ Es, const float* __restrict__ Ed,
                                              int* __restrict__ cnt, unsigned short* __restrict__ bucket,
                                              float* __restrict__ psumF, unsigned* __restrict__ done,
                                              float* __restrict__ hstat) {
    __shared__ float4 ls[4];
    __shared__ int amLast;
    int e = blockIdx.x * 256 + threadIdx.x;
    int tid = threadIdx.x, lane = tid & 63, wid = tid >> 6;
    float4 p = {0.f, 0.f, 0.f, 0.f};
    if (e < TE) {
        int si = e < EE ? es[e] : e - EE;
        int di = e < EE ? ed[e] : e - EE;
        int pos = atomicAdd(cnt + di, 1);
        if (pos < CAP) bucket[di * CAP + pos] = (unsigned short)si;   // clamp for memory safety
        float4 a = ((const float4*)Es)[si];
        float4 d = ((const float4*)Ed)[di];
        p.x = a.x * d.x; p.y = a.y * d.y; p.z = a.z * d.z; p.w = a.w * d.w;
    }
    #pragma unroll
    for (int m = 32; m > 0; m >>= 1) {
        p.x += __shfl_xor(p.x, m, 64);
        p.y += __shfl_xor(p.y, m, 64);
        p.z += __shfl_xor(p.z, m, 64);
        p.w += __shfl_xor(p.w, m, 64);
    }
    if (lane == 0) ls[wid] = p;
    __syncthreads();
    if (tid == 0) {
        float4 t;
        t.x = ls[0].x + ls[1].x + ls[2].x + ls[3].x;
        t.y = ls[0].y + ls[1].y + ls[2].y + ls[3].y;
        t.z = ls[0].z + ls[1].z + ls[2].z + ls[3].z;
        t.w = ls[0].w + ls[1].w + ls[2].w + ls[3].w;
        // device-coherent publish of this block's partial
        atomicExch(psumF + blockIdx.x * 4 + 0, t.x);
        atomicExch(psumF + blockIdx.x * 4 + 1, t.y);
        atomicExch(psumF + blockIdx.x * 4 + 2, t.z);
        atomicExch(psumF + blockIdx.x * 4 + 3, t.w);
        __threadfence();
        unsigned v = atomicAdd(done, 1u);
        amLast = (v == NB_SCORE - 1);
    }
    __syncthreads();
    if (amLast) {      // block-uniform: whole block participates in the combine
        __threadfence();
        float4 z = {0.f, 0.f, 0.f, 0.f};
        for (int i = tid; i < NB_SCORE; i += 256) {
            z.x += atomicAdd(psumF + i * 4 + 0, 0.0f);   // device-coherent read
            z.y += atomicAdd(psumF + i * 4 + 1, 0.0f);
            z.z += atomicAdd(psumF + i * 4 + 2, 0.0f);
            z.w += atomicAdd(psumF + i * 4 + 3, 0.0f);
        }
        #pragma unroll
        for (int m = 32; m > 0; m >>= 1) {
            z.x += __shfl_xor(z.x, m, 64);
            z.y += __shfl_xor(z.y, m, 64);
            z.z += __shfl_xor(z.z, m, 64);
            z.w += __shfl_xor(z.w, m, 64);
        }
        __syncthreads();
        if (lane == 0) ls[wid] = z;
        __syncthreads();
        if (tid == 0) {
            float4 t;
            t.x = ls[0].x + ls[1].x + ls[2].x + ls[3].x;
            t.y = ls[0].y + ls[1].y + ls[2].y + ls[3].y;
            t.z = ls[0].z + ls[1].z + ls[2].z + ls[3].z;
            t.w = ls[0].w + ls[1].w + ls[2].w + ls[3].w;
            hstat[0] = 1.0f / t.x; hstat[1] = 1.0f / t.y;
            hstat[2] = 1.0f / t.z; hstat[3] = 1.0f / t.w;
        }
    }
}

// ---------------- gather: out[n] = b + invZ*Ed[n] * sum_{j<cnt[n]} Es[s_j] * h16[s_j] ----------------
// one wave per dst node; u16 bucket; x16 unroll (avg deg ~17) for deep MLP
__global__ __launch_bounds__(256) void k_gather(const int* __restrict__ cnt,
                                                const unsigned short* __restrict__ bucket,
                                                const float* __restrict__ Es, const float* __restrict__ Ed,
                                                const _Float16* __restrict__ h16, const float* __restrict__ b,
                                                const float* __restrict__ hstat, float* __restrict__ out) {
    int n = blockIdx.x * 4 + (threadIdx.x >> 6);
    int lane = threadIdx.x & 63;
    int head = lane >> 4;
    int len = cnt[n]; len = len < CAP ? len : CAP;
    const unsigned short* bsi = bucket + n * CAP;
    const half4v* h4 = (const half4v*)h16;   // index: s*64 + lane
    float4 a0 = {0.f, 0.f, 0.f, 0.f}, a1 = a0, a2 = a0, a3 = a0;
    int j = 0;
    for (; j + 15 < len; j += 16) {
        int s[16];
        float w[16];
        #pragma unroll
        for (int q = 0; q < 16; ++q) s[q] = bsi[j + q];
        #pragma unroll
        for (int q = 0; q < 16; ++q) w[q] = Es[s[q] * 4 + head];
        half4v v[16];
        #pragma unroll
        for (int q = 0; q < 16; ++q) v[q] = h4[s[q] * 64 + lane];
        #pragma unroll
        for (int q = 0; q < 16; q += 4) {
            a0.x += w[q] * (float)v[q].x;     a0.y += w[q] * (float)v[q].y;
            a0.z += w[q] * (float)v[q].z;     a0.w += w[q] * (float)v[q].w;
            a1.x += w[q+1] * (float)v[q+1].x; a1.y += w[q+1] * (float)v[q+1].y;
            a1.z += w[q+1] * (float)v[q+1].z; a1.w += w[q+1] * (float)v[q+1].w;
            a2.x += w[q+2] * (float)v[q+2].x; a2.y += w[q+2] * (float)v[q+2].y;
            a2.z += w[q+2] * (float)v[q+2].z; a2.w += w[q+2] * (float)v[q+2].w;
            a3.x += w[q+3] * (float)v[q+3].x; a3.y += w[q+3] * (float)v[q+3].y;
            a3.z += w[q+3] * (float)v[q+3].z; a3.w += w[q+3] * (float)v[q+3].w;
        }
    }
    for (; j + 7 < len; j += 8) {
        int s0 = bsi[j],     s1 = bsi[j + 1], s2 = bsi[j + 2], s3 = bsi[j + 3];
        int s4 = bsi[j + 4], s5 = bsi[j + 5], s6 = bsi[j + 6], s7 = bsi[j + 7];
        float w0 = Es[s0 * 4 + head], w1 = Es[s1 * 4 + head];
        float w2 = Es[s2 * 4 + head], w3 = Es[s3 * 4 + head];
        float w4 = Es[s4 * 4 + head], w5 = Es[s5 * 4 + head];
        float w6 = Es[s6 * 4 + head], w7 = Es[s7 * 4 + head];
        half4v v0 = h4[s0 * 64 + lane], v1 = h4[s1 * 64 + lane];
        half4v v2 = h4[s2 * 64 + lane], v3 = h4[s3 * 64 + lane];
        half4v v4 = h4[s4 * 64 + lane], v5 = h4[s5 * 64 + lane];
        half4v v6 = h4[s6 * 64 + lane], v7 = h4[s7 * 64 + lane];
        a0.x += w0 * (float)v0.x; a0.y += w0 * (float)v0.y; a0.z += w0 * (float)v0.z; a0.w += w0 * (float)v0.w;
        a1.x += w1 * (float)v1.x; a1.y += w1 * (float)v1.y; a1.z += w1 * (float)v1.z; a1.w += w1 * (float)v1.w;
        a2.x += w2 * (float)v2.x; a2.y += w2 * (float)v2.y; a2.z += w2 * (float)v2.z; a2.w += w2 * (float)v2.w;
        a3.x += w3 * (float)v3.x; a3.y += w3 * (float)v3.y; a3.z += w3 * (float)v3.z; a3.w += w3 * (float)v3.w;
        a0.x += w4 * (float)v4.x; a0.y += w4 * (float)v4.y; a0.z += w4 * (float)v4.z; a0.w += w4 * (float)v4.w;
        a1.x += w5 * (float)v5.x; a1.y += w5 * (float)v5.y; a1.z += w5 * (float)v5.z; a1.w += w5 * (float)v5.w;
        a2.x += w6 * (float)v6.x; a2.y += w6 * (float)v6.y; a2.z += w6 * (float)v6.z; a2.w += w6 * (float)v6.w;
        a3.x += w7 * (float)v7.x; a3.y += w7 * (float)v7.y; a3.z += w7 * (float)v7.z; a3.w += w7 * (float)v7.w;
    }
    for (; j + 3 < len; j += 4) {
        int s0 = bsi[j], s1 = bsi[j + 1], s2 = bsi[j + 2], s3 = bsi[j + 3];
        float w0 = Es[s0 * 4 + head], w1 = Es[s1 * 4 + head];
        float w2 = Es[s2 * 4 + head], w3 = Es[s3 * 4 + head];
        half4v v0 = h4[s0 * 64 + lane], v1 = h4[s1 * 64 + lane];
        half4v v2 = h4[s2 * 64 + lane], v3 = h4[s3 * 64 + lane];
        a0.x += w0 * (float)v0.x; a0.y += w0 * (float)v0.y; a0.z += w0 * (float)v0.z; a0.w += w0 * (float)v0.w;
        a1.x += w1 * (float)v1.x; a1.y += w1 * (float)v1.y; a1.z += w1 * (float)v1.z; a1.w += w1 * (float)v1.w;
        a2.x += w2 * (float)v2.x; a2.y += w2 * (float)v2.y; a2.z += w2 * (float)v2.z; a2.w += w2 * (float)v2.w;
        a3.x += w3 * (float)v3.x; a3.y += w3 * (float)v3.y; a3.z += w3 * (float)v3.z; a3.w += w3 * (float)v3.w;
    }
    for (; j < len; ++j) {
        int s = bsi[j];
        float w = Es[s * 4 + head];
        half4v hv = h4[s * 64 + lane];
        a0.x += w * (float)hv.x; a0.y += w * (float)hv.y; a0.z += w * (float)hv.z; a0.w += w * (float)hv.w;
    }
    float scale = hstat[head] * Ed[n * 4 + head];
    float4 bb = ((const float4*)b)[lane];
    float4 o;
    o.x = bb.x + scale * (a0.x + a1.x + a2.x + a3.x);
    o.y = bb.y + scale * (a0.y + a1.y + a2.y + a3.y);
    o.z = bb.z + scale * (a0.z + a1.z + a2.z + a3.z);
    o.w = bb.w + scale * (a0.w + a1.w + a2.w + a3.w);
    ((float4*)out)[n * 64 + lane] = o;
}

extern "C" void kernel_launch(void* const* d_in, const int* in_sizes, int n_in,
                              void* d_out, int out_size, void* d_ws, size_t ws_size,
                              hipStream_t stream) {
    const float* x   = (const float*)d_in[0];
    const float* W   = (const float*)d_in[1];
    const float* att = (const float*)d_in[2];
    const float* b   = (const float*)d_in[3];
    const int*  eidx = (const int*)d_in[4];
    const int* es = eidx;        // edge_index[0] : sources
    const int* ed = eidx + EE;   // edge_index[1] : destinations
    float* out = (float*)d_out;

    float* ws = (float*)d_ws;
    _Float16* h16 = (_Float16*)ws;                     // 5,120,000 fp16 = 10.24 MB
    float* Es     = (float*)(h16 + NN * 256);          // 80,000 f (exp tables)
    float* Ed     = Es + NN * 4;                       // 80,000 f
    int*   cnt    = (int*)(Ed + NN * 4);               // 20,000 i (bin counters/cursors)
    unsigned short* bucket = (unsigned short*)(cnt + NN);  // 20,000*96 u16 = 3.84 MB
    float* psumF  = (float*)(bucket + NN * CAP);       // NB_SCORE*4 f
    unsigned* done = (unsigned*)(psumF + NB_SCORE * 4); // 1 u32
    float* hstat  = (float*)(done + 3);                // 4 f (invZ), 16B-aligned-ish
    _Float16* Wh  = (_Float16*)(hstat + 12);           // 65,536 fp16 (hi split, k-blocked)
    _Float16* Wl  = Wh + 256 * 256;                    // 65,536 fp16 (lo split, k-blocked)

    k_wsplit<<<256, 256, 0, stream>>>(W, Wh, Wl, done);
    k_gemm  <<<NB_GEMM, 256, 0, stream>>>(x, Wh, Wl, att, h16, Es, Ed, cnt);
    k_fill  <<<NB_SCORE, 256, 0, stream>>>(es, ed, Es, Ed, cnt, bucket, psumF, done, hstat);
    k_gather<<<NN / 4, 256, 0, stream>>>(cnt, bucket, Es, Ed, h16, b, hstat, out);
}

// Round 16
// 84.499 us; speedup vs baseline: 1.4696x; 1.4696x over previous
//
#include <hip/hip_runtime.h>

#define NN 20000
#define EE 320000
#define TE 340000        // EE + NN self loops
#define NEG 0.2f
#define NB_SCORE 1329    // ceil(TE/256)
#define NB_GEMM 625      // 20000 / 32
#define CAP 96           // max bin capacity (deg ~ 1+Poisson(16); P(>95) ~ 1e-40)

typedef __attribute__((ext_vector_type(8))) _Float16 half8;
typedef __attribute__((ext_vector_type(4))) _Float16 half4v;
typedef __attribute__((ext_vector_type(4))) float f32x4;

__device__ __forceinline__ float lrelu(float v) { return v > 0.f ? v : NEG * v; }

// ---------------- W -> fp16 split tables in k-blocked layout: Wb[k>>3][col][k&7] ----------------
__global__ __launch_bounds__(256) void k_wsplit(const float* __restrict__ W,
                                                _Float16* __restrict__ Wh, _Float16* __restrict__ Wl) {
    int c = blockIdx.x;      // 256 cols
    int k = threadIdx.x;     // 256 k
    float w = W[k * 256 + c];
    _Float16 hi = (_Float16)w;
    _Float16 lo = (_Float16)(w - (float)hi);
    int idx = (k >> 3) * 2048 + c * 8 + (k & 7);
    Wh[idx] = hi;
    Wl[idx] = lo;
}

// ---------------- MFMA GEMM: h16 = fp16(x @ W), Es/Ed = exp(alpha) directly ----------------
// 625 blocks x 256 thr (4 waves); 32 rows/block; wave = 2 row-tiles x 64 cols (= head wid).
__global__ __launch_bounds__(256, 4) void k_gemm(const float* __restrict__ x,
                                                 const _Float16* __restrict__ Wh,
                                                 const _Float16* __restrict__ Wl,
                                                 const float* __restrict__ att, _Float16* __restrict__ h16,
                                                 float* __restrict__ Es, float* __restrict__ Ed,
                                                 int* __restrict__ cnt) {
    __shared__ _Float16 xh[32][264];   // 16.5 KB
    __shared__ _Float16 xl[32][264];   // 16.5 KB
    const int tid = threadIdx.x;
    const int r0 = blockIdx.x * 32;

    if (tid < 32) cnt[r0 + tid] = 0;   // zero bin counters (cursors for k_fill)

    const float4* x4 = (const float4*)x;
    #pragma unroll
    for (int i = 0; i < 8; ++i) {
        int slot = tid + i * 256;      // 2048 float4 slots = 32 rows x 64
        int row = slot >> 6, c4 = slot & 63;
        float4 v = x4[(r0 + row) * 64 + c4];
        _Float16 h0 = (_Float16)v.x, h1 = (_Float16)v.y, h2 = (_Float16)v.z, h3 = (_Float16)v.w;
        half4v hv = {h0, h1, h2, h3};
        half4v lv = {(_Float16)(v.x - (float)h0), (_Float16)(v.y - (float)h1),
                     (_Float16)(v.z - (float)h2), (_Float16)(v.w - (float)h3)};
        *(half4v*)&xh[row][c4 * 4] = hv;
        *(half4v*)&xl[row][c4 * 4] = lv;
    }
    __syncthreads();

    const int lane = tid & 63, wid = tid >> 6;
    const int ch = wid;                         // col-quarter = head of this wave
    const int grp = lane >> 4, li = lane & 15;  // k-group / row-or-col index in fragment

    f32x4 acc[2][4];
    #pragma unroll
    for (int rt = 0; rt < 2; ++rt)
        #pragma unroll
        for (int i = 0; i < 4; ++i) acc[rt][i] = (f32x4){0.f, 0.f, 0.f, 0.f};

    const _Float16* bb_h = Wh + (ch * 64 + li) * 8 + grp * 2048;
    const _Float16* bb_l = Wl + (ch * 64 + li) * 8 + grp * 2048;

    for (int ks = 0; ks < 8; ++ks) {            // K = 8 steps of 32
        half8 ah0 = *(const half8*)&xh[li][ks * 32 + grp * 8];
        half8 al0 = *(const half8*)&xl[li][ks * 32 + grp * 8];
        half8 ah1 = *(const half8*)&xh[16 + li][ks * 32 + grp * 8];
        half8 al1 = *(const half8*)&xl[16 + li][ks * 32 + grp * 8];
        const _Float16* ph = bb_h + ks * 8192;
        const _Float16* pl = bb_l + ks * 8192;
        #pragma unroll
        for (int ct = 0; ct < 4; ++ct) {        // 4 col-tiles of 16; B reused for both row-tiles
            half8 bh = *(const half8*)(ph + ct * 128);
            half8 bl = *(const half8*)(pl + ct * 128);
            acc[0][ct] = __builtin_amdgcn_mfma_f32_16x16x32_f16(ah0, bh, acc[0][ct], 0, 0, 0);
            acc[0][ct] = __builtin_amdgcn_mfma_f32_16x16x32_f16(al0, bh, acc[0][ct], 0, 0, 0);
            acc[0][ct] = __builtin_amdgcn_mfma_f32_16x16x32_f16(ah0, bl, acc[0][ct], 0, 0, 0);
            acc[0][ct] = __builtin_amdgcn_mfma_f32_16x16x32_f16(al0, bl, acc[0][ct], 0, 0, 0);
            acc[1][ct] = __builtin_amdgcn_mfma_f32_16x16x32_f16(ah1, bh, acc[1][ct], 0, 0, 0);
            acc[1][ct] = __builtin_amdgcn_mfma_f32_16x16x32_f16(al1, bh, acc[1][ct], 0, 0, 0);
            acc[1][ct] = __builtin_amdgcn_mfma_f32_16x16x32_f16(ah1, bl, acc[1][ct], 0, 0, 0);
            acc[1][ct] = __builtin_amdgcn_mfma_f32_16x16x32_f16(al1, bl, acc[1][ct], 0, 0, 0);
        }
    }

    // epilogue: h16 store + alpha partials -> Es/Ed = exp(alpha) directly.
    float pss[2][4] = {{0.f,0.f,0.f,0.f},{0.f,0.f,0.f,0.f}};
    float psd[2][4] = {{0.f,0.f,0.f,0.f},{0.f,0.f,0.f,0.f}};
    #pragma unroll
    for (int rt = 0; rt < 2; ++rt) {
        #pragma unroll
        for (int ct = 0; ct < 4; ++ct) {
            int cl = ct * 16 + li;                   // col within head, 0..63
            float avc = att[ch * 128 + cl];          // a_src coef
            float dvc = att[ch * 128 + 64 + cl];     // a_dst coef
            #pragma unroll
            for (int reg = 0; reg < 4; ++reg) {
                float v = acc[rt][ct][reg];
                h16[(r0 + rt * 16 + grp * 4 + reg) * 256 + ch * 64 + cl] = (_Float16)v;
                float l = lrelu(v);
                pss[rt][reg] += l * avc;
                psd[rt][reg] += l * dvc;
            }
        }
    }
    #pragma unroll
    for (int rt = 0; rt < 2; ++rt)
        #pragma unroll
        for (int reg = 0; reg < 4; ++reg) {
            #pragma unroll
            for (int m = 1; m < 16; m <<= 1) {
                pss[rt][reg] += __shfl_xor(pss[rt][reg], m, 64);
                psd[rt][reg] += __shfl_xor(psd[rt][reg], m, 64);
            }
        }
    if (li == 0) {
        #pragma unroll
        for (int rt = 0; rt < 2; ++rt)
            #pragma unroll
            for (int reg = 0; reg < 4; ++reg) {
                int row = r0 + rt * 16 + grp * 4 + reg;
                Es[row * 4 + ch] = expf(pss[rt][reg]);
                Ed[row * 4 + ch] = expf(psd[rt][reg]);
            }
    }
}

// ---------------- fill: u16 bucket scatter (cursor = cnt) + Z partials (plain stores) ----------------
__global__ __launch_bounds__(256) void k_fill(const int* __restrict__ es, const int* __restrict__ ed,
                                              const float* __restrict__ Es, const float* __restrict__ Ed,
                                              int* __restrict__ cnt, unsigned short* __restrict__ bucket,
                                              float4* __restrict__ psum) {
    __shared__ float4 ls[4];
    int e = blockIdx.x * 256 + threadIdx.x;
    int tid = threadIdx.x, lane = tid & 63, wid = tid >> 6;
    float4 p = {0.f, 0.f, 0.f, 0.f};
    if (e < TE) {
        int si = e < EE ? es[e] : e - EE;
        int di = e < EE ? ed[e] : e - EE;
        int pos = atomicAdd(cnt + di, 1);
        if (pos < CAP) bucket[di * CAP + pos] = (unsigned short)si;   // clamp for memory safety
        float4 a = ((const float4*)Es)[si];
        float4 d = ((const float4*)Ed)[di];
        p.x = a.x * d.x; p.y = a.y * d.y; p.z = a.z * d.z; p.w = a.w * d.w;
    }
    #pragma unroll
    for (int m = 32; m > 0; m >>= 1) {
        p.x += __shfl_xor(p.x, m, 64);
        p.y += __shfl_xor(p.y, m, 64);
        p.z += __shfl_xor(p.z, m, 64);
        p.w += __shfl_xor(p.w, m, 64);
    }
    if (lane == 0) ls[wid] = p;
    __syncthreads();
    if (tid == 0) {
        float4 t;
        t.x = ls[0].x + ls[1].x + ls[2].x + ls[3].x;
        t.y = ls[0].y + ls[1].y + ls[2].y + ls[3].y;
        t.z = ls[0].z + ls[1].z + ls[2].z + ls[3].z;
        t.w = ls[0].w + ls[1].w + ls[2].w + ls[3].w;
        psum[blockIdx.x] = t;
    }
}

// ---------------- combine psum -> invZ ----------------
__global__ __launch_bounds__(256) void k_comb(const float4* __restrict__ psum, float* __restrict__ hstat) {
    __shared__ float4 zred[4];
    int tid = threadIdx.x, lane = tid & 63, wid = tid >> 6;
    float4 z = {0.f, 0.f, 0.f, 0.f};
    for (int i = tid; i < NB_SCORE; i += 256) {
        float4 s = psum[i];
        z.x += s.x; z.y += s.y; z.z += s.z; z.w += s.w;
    }
    #pragma unroll
    for (int m = 32; m > 0; m >>= 1) {
        z.x += __shfl_xor(z.x, m, 64);
        z.y += __shfl_xor(z.y, m, 64);
        z.z += __shfl_xor(z.z, m, 64);
        z.w += __shfl_xor(z.w, m, 64);
    }
    if (lane == 0) zred[wid] = z;
    __syncthreads();
    if (tid == 0) {
        float4 t;
        t.x = zred[0].x + zred[1].x + zred[2].x + zred[3].x;
        t.y = zred[0].y + zred[1].y + zred[2].y + zred[3].y;
        t.z = zred[0].z + zred[1].z + zred[2].z + zred[3].z;
        t.w = zred[0].w + zred[1].w + zred[2].w + zred[3].w;
        hstat[0] = 1.0f / t.x; hstat[1] = 1.0f / t.y;
        hstat[2] = 1.0f / t.z; hstat[3] = 1.0f / t.w;
    }
}

// ---------------- gather: out[n] = b + invZ*Ed[n] * sum_{j<cnt[n]} Es[s_j] * h16[s_j] ----------------
// one wave per dst node; u16 bucket; x16 unroll (avg deg ~17) for deep MLP
__global__ __launch_bounds__(256) void k_gather(const int* __restrict__ cnt,
                                                const unsigned short* __restrict__ bucket,
                                                const float* __restrict__ Es, const float* __restrict__ Ed,
                                                const _Float16* __restrict__ h16, const float* __restrict__ b,
                                                const float* __restrict__ hstat, float* __restrict__ out) {
    int n = blockIdx.x * 4 + (threadIdx.x >> 6);
    int lane = threadIdx.x & 63;
    int head = lane >> 4;
    int len = cnt[n]; len = len < CAP ? len : CAP;
    const unsigned short* bsi = bucket + n * CAP;
    const half4v* h4 = (const half4v*)h16;   // index: s*64 + lane
    float4 a0 = {0.f, 0.f, 0.f, 0.f}, a1 = a0, a2 = a0, a3 = a0;
    int j = 0;
    for (; j + 15 < len; j += 16) {
        int s[16];
        float w[16];
        #pragma unroll
        for (int q = 0; q < 16; ++q) s[q] = bsi[j + q];
        #pragma unroll
        for (int q = 0; q < 16; ++q) w[q] = Es[s[q] * 4 + head];
        half4v v[16];
        #pragma unroll
        for (int q = 0; q < 16; ++q) v[q] = h4[s[q] * 64 + lane];
        #pragma unroll
        for (int q = 0; q < 16; q += 4) {
            a0.x += w[q] * (float)v[q].x;     a0.y += w[q] * (float)v[q].y;
            a0.z += w[q] * (float)v[q].z;     a0.w += w[q] * (float)v[q].w;
            a1.x += w[q+1] * (float)v[q+1].x; a1.y += w[q+1] * (float)v[q+1].y;
            a1.z += w[q+1] * (float)v[q+1].z; a1.w += w[q+1] * (float)v[q+1].w;
            a2.x += w[q+2] * (float)v[q+2].x; a2.y += w[q+2] * (float)v[q+2].y;
            a2.z += w[q+2] * (float)v[q+2].z; a2.w += w[q+2] * (float)v[q+2].w;
            a3.x += w[q+3] * (float)v[q+3].x; a3.y += w[q+3] * (float)v[q+3].y;
            a3.z += w[q+3] * (float)v[q+3].z; a3.w += w[q+3] * (float)v[q+3].w;
        }
    }
    for (; j + 7 < len; j += 8) {
        int s0 = bsi[j],     s1 = bsi[j + 1], s2 = bsi[j + 2], s3 = bsi[j + 3];
        int s4 = bsi[j + 4], s5 = bsi[j + 5], s6 = bsi[j + 6], s7 = bsi[j + 7];
        float w0 = Es[s0 * 4 + head], w1 = Es[s1 * 4 + head];
        float w2 = Es[s2 * 4 + head], w3 = Es[s3 * 4 + head];
        float w4 = Es[s4 * 4 + head], w5 = Es[s5 * 4 + head];
        float w6 = Es[s6 * 4 + head], w7 = Es[s7 * 4 + head];
        half4v v0 = h4[s0 * 64 + lane], v1 = h4[s1 * 64 + lane];
        half4v v2 = h4[s2 * 64 + lane], v3 = h4[s3 * 64 + lane];
        half4v v4 = h4[s4 * 64 + lane], v5 = h4[s5 * 64 + lane];
        half4v v6 = h4[s6 * 64 + lane], v7 = h4[s7 * 64 + lane];
        a0.x += w0 * (float)v0.x; a0.y += w0 * (float)v0.y; a0.z += w0 * (float)v0.z; a0.w += w0 * (float)v0.w;
        a1.x += w1 * (float)v1.x; a1.y += w1 * (float)v1.y; a1.z += w1 * (float)v1.z; a1.w += w1 * (float)v1.w;
        a2.x += w2 * (float)v2.x; a2.y += w2 * (float)v2.y; a2.z += w2 * (float)v2.z; a2.w += w2 * (float)v2.w;
        a3.x += w3 * (float)v3.x; a3.y += w3 * (float)v3.y; a3.z += w3 * (float)v3.z; a3.w += w3 * (float)v3.w;
        a0.x += w4 * (float)v4.x; a0.y += w4 * (float)v4.y; a0.z += w4 * (float)v4.z; a0.w += w4 * (float)v4.w;
        a1.x += w5 * (float)v5.x; a1.y += w5 * (float)v5.y; a1.z += w5 * (float)v5.z; a1.w += w5 * (float)v5.w;
        a2.x += w6 * (float)v6.x; a2.y += w6 * (float)v6.y; a2.z += w6 * (float)v6.z; a2.w += w6 * (float)v6.w;
        a3.x += w7 * (float)v7.x; a3.y += w7 * (float)v7.y; a3.z += w7 * (float)v7.z; a3.w += w7 * (float)v7.w;
    }
    for (; j + 3 < len; j += 4) {
        int s0 = bsi[j], s1 = bsi[j + 1], s2 = bsi[j + 2], s3 = bsi[j + 3];
        float w0 = Es[s0 * 4 + head], w1 = Es[s1 * 4 + head];
        float w2 = Es[s2 * 4 + head], w3 = Es[s3 * 4 + head];
        half4v v0 = h4[s0 * 64 + lane], v1 = h4[s1 * 64 + lane];
        half4v v2 = h4[s2 * 64 + lane], v3 = h4[s3 * 64 + lane];
        a0.x += w0 * (float)v0.x; a0.y += w0 * (float)v0.y; a0.z += w0 * (float)v0.z; a0.w += w0 * (float)v0.w;
        a1.x += w1 * (float)v1.x; a1.y += w1 * (float)v1.y; a1.z += w1 * (float)v1.z; a1.w += w1 * (float)v1.w;
        a2.x += w2 * (float)v2.x; a2.y += w2 * (float)v2.y; a2.z += w2 * (float)v2.z; a2.w += w2 * (float)v2.w;
        a3.x += w3 * (float)v3.x; a3.y += w3 * (float)v3.y; a3.z += w3 * (float)v3.z; a3.w += w3 * (float)v3.w;
    }
    for (; j < len; ++j) {
        int s = bsi[j];
        float w = Es[s * 4 + head];
        half4v hv = h4[s * 64 + lane];
        a0.x += w * (float)hv.x; a0.y += w * (float)hv.y; a0.z += w * (float)hv.z; a0.w += w * (float)hv.w;
    }
    float scale = hstat[head] * Ed[n * 4 + head];
    float4 bb = ((const float4*)b)[lane];
    float4 o;
    o.x = bb.x + scale * (a0.x + a1.x + a2.x + a3.x);
    o.y = bb.y + scale * (a0.y + a1.y + a2.y + a3.y);
    o.z = bb.z + scale * (a0.z + a1.z + a2.z + a3.z);
    o.w = bb.w + scale * (a0.w + a1.w + a2.w + a3.w);
    ((float4*)out)[n * 64 + lane] = o;
}

extern "C" void kernel_launch(void* const* d_in, const int* in_sizes, int n_in,
                              void* d_out, int out_size, void* d_ws, size_t ws_size,
                              hipStream_t stream) {
    const float* x   = (const float*)d_in[0];
    const float* W   = (const float*)d_in[1];
    const float* att = (const float*)d_in[2];
    const float* b   = (const float*)d_in[3];
    const int*  eidx = (const int*)d_in[4];
    const int* es = eidx;        // edge_index[0] : sources
    const int* ed = eidx + EE;   // edge_index[1] : destinations
    float* out = (float*)d_out;

    float* ws = (float*)d_ws;
    _Float16* h16 = (_Float16*)ws;                     // 5,120,000 fp16 = 10.24 MB
    float* Es     = (float*)(h16 + NN * 256);          // 80,000 f (exp tables)
    float* Ed     = Es + NN * 4;                       // 80,000 f
    int*   cnt    = (int*)(Ed + NN * 4);               // 20,000 i (bin counters/cursors)
    unsigned short* bucket = (unsigned short*)(cnt + NN);  // 20,000*96 u16 = 3.84 MB
    float4* psum  = (float4*)(bucket + NN * CAP);      // NB_SCORE f4
    float* hstat  = (float*)(psum + NB_SCORE + 1);     // 4 f (invZ)
    _Float16* Wh  = (_Float16*)(hstat + 12);           // 65,536 fp16 (hi split, k-blocked)
    _Float16* Wl  = Wh + 256 * 256;                    // 65,536 fp16 (lo split, k-blocked)

    k_wsplit<<<256, 256, 0, stream>>>(W, Wh, Wl);
    k_gemm  <<<NB_GEMM, 256, 0, stream>>>(x, Wh, Wl, att, h16, Es, Ed, cnt);
    k_fill  <<<NB_SCORE, 256, 0, stream>>>(es, ed, Es, Ed, cnt, bucket, psum);
    k_comb  <<<1, 256, 0, stream>>>(psum, hstat);
    k_gather<<<NN / 4, 256, 0, stream>>>(cnt, bucket, Es, Ed, h16, b, hstat, out);
}

// Round 17
// 82.858 us; speedup vs baseline: 1.4987x; 1.0198x over previous
//
#include <hip/hip_runtime.h>

#define NN 20000
#define EE 320000
#define TE 340000        // EE + NN self loops
#define NEG 0.2f
#define NB_FILL 665      // ceil(TE/512), 2 edges/thread
#define NB_GEMM 625      // 20000 / 32
#define CAP 96           // max bin capacity (deg ~ 1+Poisson(16); P(>95) ~ 1e-40)

typedef __attribute__((ext_vector_type(8))) _Float16 half8;
typedef __attribute__((ext_vector_type(4))) _Float16 half4v;
typedef __attribute__((ext_vector_type(4))) float f32x4;

__device__ __forceinline__ float lrelu(float v) { return v > 0.f ? v : NEG * v; }

// ---------------- W -> fp16 split tables (k-blocked: Wb[k>>3][col][k&7]) + cnt zero ----------------
__global__ __launch_bounds__(256) void k_wsplit(const float* __restrict__ W,
                                                _Float16* __restrict__ Wh, _Float16* __restrict__ Wl,
                                                int* __restrict__ cnt) {
    int z = blockIdx.x * 256 + threadIdx.x;
    if (z < NN) cnt[z] = 0;            // zero bin counters (cursors for k_fill, 2 kernels later)
    int c = blockIdx.x;      // 256 cols
    int k = threadIdx.x;     // 256 k
    float w = W[k * 256 + c];
    _Float16 hi = (_Float16)w;
    _Float16 lo = (_Float16)(w - (float)hi);
    int idx = (k >> 3) * 2048 + c * 8 + (k & 7);
    Wh[idx] = hi;
    Wl[idx] = lo;
}

// ---------------- MFMA GEMM: h16 = fp16(x @ W), Es/Ed = exp(alpha) directly ----------------
// 625 blocks x 256 thr (4 waves); 32 rows/block; wave = 2 row-tiles x 64 cols (= head wid).
// 3-term fp16 split (ah*bh + al*bh + ah*bl): dropped al*bl ~ 2^-22 -- far below fp16 h16 rounding.
__global__ __launch_bounds__(256, 4) void k_gemm(const float* __restrict__ x,
                                                 const _Float16* __restrict__ Wh,
                                                 const _Float16* __restrict__ Wl,
                                                 const float* __restrict__ att, _Float16* __restrict__ h16,
                                                 float* __restrict__ Es, float* __restrict__ Ed) {
    __shared__ _Float16 xh[32][264];   // 16.5 KB
    __shared__ _Float16 xl[32][264];   // 16.5 KB
    const int tid = threadIdx.x;
    const int r0 = blockIdx.x * 32;

    const float4* x4 = (const float4*)x;
    #pragma unroll
    for (int i = 0; i < 8; ++i) {
        int slot = tid + i * 256;      // 2048 float4 slots = 32 rows x 64
        int row = slot >> 6, c4 = slot & 63;
        float4 v = x4[(r0 + row) * 64 + c4];
        _Float16 h0 = (_Float16)v.x, h1 = (_Float16)v.y, h2 = (_Float16)v.z, h3 = (_Float16)v.w;
        half4v hv = {h0, h1, h2, h3};
        half4v lv = {(_Float16)(v.x - (float)h0), (_Float16)(v.y - (float)h1),
                     (_Float16)(v.z - (float)h2), (_Float16)(v.w - (float)h3)};
        *(half4v*)&xh[row][c4 * 4] = hv;
        *(half4v*)&xl[row][c4 * 4] = lv;
    }
    __syncthreads();

    const int lane = tid & 63, wid = tid >> 6;
    const int ch = wid;                         // col-quarter = head of this wave
    const int grp = lane >> 4, li = lane & 15;  // k-group / row-or-col index in fragment

    f32x4 acc[2][4];
    #pragma unroll
    for (int rt = 0; rt < 2; ++rt)
        #pragma unroll
        for (int i = 0; i < 4; ++i) acc[rt][i] = (f32x4){0.f, 0.f, 0.f, 0.f};

    const _Float16* bb_h = Wh + (ch * 64 + li) * 8 + grp * 2048;
    const _Float16* bb_l = Wl + (ch * 64 + li) * 8 + grp * 2048;

    for (int ks = 0; ks < 8; ++ks) {            // K = 8 steps of 32
        half8 ah0 = *(const half8*)&xh[li][ks * 32 + grp * 8];
        half8 al0 = *(const half8*)&xl[li][ks * 32 + grp * 8];
        half8 ah1 = *(const half8*)&xh[16 + li][ks * 32 + grp * 8];
        half8 al1 = *(const half8*)&xl[16 + li][ks * 32 + grp * 8];
        const _Float16* ph = bb_h + ks * 8192;
        const _Float16* pl = bb_l + ks * 8192;
        #pragma unroll
        for (int ct = 0; ct < 4; ++ct) {        // 4 col-tiles of 16; B reused for both row-tiles
            half8 bh = *(const half8*)(ph + ct * 128);
            half8 bl = *(const half8*)(pl + ct * 128);
            acc[0][ct] = __builtin_amdgcn_mfma_f32_16x16x32_f16(ah0, bh, acc[0][ct], 0, 0, 0);
            acc[0][ct] = __builtin_amdgcn_mfma_f32_16x16x32_f16(al0, bh, acc[0][ct], 0, 0, 0);
            acc[0][ct] = __builtin_amdgcn_mfma_f32_16x16x32_f16(ah0, bl, acc[0][ct], 0, 0, 0);
            acc[1][ct] = __builtin_amdgcn_mfma_f32_16x16x32_f16(ah1, bh, acc[1][ct], 0, 0, 0);
            acc[1][ct] = __builtin_amdgcn_mfma_f32_16x16x32_f16(al1, bh, acc[1][ct], 0, 0, 0);
            acc[1][ct] = __builtin_amdgcn_mfma_f32_16x16x32_f16(ah1, bl, acc[1][ct], 0, 0, 0);
        }
    }

    // epilogue: h16 store + alpha partials -> Es/Ed = exp(alpha) directly.
    float pss[2][4] = {{0.f,0.f,0.f,0.f},{0.f,0.f,0.f,0.f}};
    float psd[2][4] = {{0.f,0.f,0.f,0.f},{0.f,0.f,0.f,0.f}};
    #pragma unroll
    for (int rt = 0; rt < 2; ++rt) {
        #pragma unroll
        for (int ct = 0; ct < 4; ++ct) {
            int cl = ct * 16 + li;                   // col within head, 0..63
            float avc = att[ch * 128 + cl];          // a_src coef
            float dvc = att[ch * 128 + 64 + cl];     // a_dst coef
            #pragma unroll
            for (int reg = 0; reg < 4; ++reg) {
                float v = acc[rt][ct][reg];
                h16[(r0 + rt * 16 + grp * 4 + reg) * 256 + ch * 64 + cl] = (_Float16)v;
                float l = lrelu(v);
                pss[rt][reg] += l * avc;
                psd[rt][reg] += l * dvc;
            }
        }
    }
    #pragma unroll
    for (int rt = 0; rt < 2; ++rt)
        #pragma unroll
        for (int reg = 0; reg < 4; ++reg) {
            #pragma unroll
            for (int m = 1; m < 16; m <<= 1) {
                pss[rt][reg] += __shfl_xor(pss[rt][reg], m, 64);
                psd[rt][reg] += __shfl_xor(psd[rt][reg], m, 64);
            }
        }
    if (li == 0) {
        #pragma unroll
        for (int rt = 0; rt < 2; ++rt)
            #pragma unroll
            for (int reg = 0; reg < 4; ++reg) {
                int row = r0 + rt * 16 + grp * 4 + reg;
                Es[row * 4 + ch] = expf(pss[rt][reg]);
                Ed[row * 4 + ch] = expf(psd[rt][reg]);
            }
    }
}

// ---------------- fill: u16 bucket scatter + Z partials; 2 edges/thread for MLP ----------------
__global__ __launch_bounds__(256) void k_fill(const int* __restrict__ es, const int* __restrict__ ed,
                                              const float* __restrict__ Es, const float* __restrict__ Ed,
                                              int* __restrict__ cnt, unsigned short* __restrict__ bucket,
                                              float4* __restrict__ psum) {
    __shared__ float4 ls[4];
    int tid = threadIdx.x, lane = tid & 63, wid = tid >> 6;
    int e0 = blockIdx.x * 512 + tid;
    int e1 = e0 + 256;
    float4 p = {0.f, 0.f, 0.f, 0.f};
    // edge 0
    int si0 = 0, di0 = 0, si1 = 0, di1 = 0;
    bool a0 = e0 < TE, a1 = e1 < TE;
    if (a0) { si0 = e0 < EE ? es[e0] : e0 - EE; di0 = e0 < EE ? ed[e0] : e0 - EE; }
    if (a1) { si1 = e1 < EE ? es[e1] : e1 - EE; di1 = e1 < EE ? ed[e1] : e1 - EE; }
    if (a0) {
        int pos = atomicAdd(cnt + di0, 1);
        if (pos < CAP) bucket[di0 * CAP + pos] = (unsigned short)si0;
    }
    if (a1) {
        int pos = atomicAdd(cnt + di1, 1);
        if (pos < CAP) bucket[di1 * CAP + pos] = (unsigned short)si1;
    }
    if (a0) {
        float4 a = ((const float4*)Es)[si0];
        float4 d = ((const float4*)Ed)[di0];
        p.x += a.x * d.x; p.y += a.y * d.y; p.z += a.z * d.z; p.w += a.w * d.w;
    }
    if (a1) {
        float4 a = ((const float4*)Es)[si1];
        float4 d = ((const float4*)Ed)[di1];
        p.x += a.x * d.x; p.y += a.y * d.y; p.z += a.z * d.z; p.w += a.w * d.w;
    }
    #pragma unroll
    for (int m = 32; m > 0; m >>= 1) {
        p.x += __shfl_xor(p.x, m, 64);
        p.y += __shfl_xor(p.y, m, 64);
        p.z += __shfl_xor(p.z, m, 64);
        p.w += __shfl_xor(p.w, m, 64);
    }
    if (lane == 0) ls[wid] = p;
    __syncthreads();
    if (tid == 0) {
        float4 t;
        t.x = ls[0].x + ls[1].x + ls[2].x + ls[3].x;
        t.y = ls[0].y + ls[1].y + ls[2].y + ls[3].y;
        t.z = ls[0].z + ls[1].z + ls[2].z + ls[3].z;
        t.w = ls[0].w + ls[1].w + ls[2].w + ls[3].w;
        psum[blockIdx.x] = t;
    }
}

// ---------------- combine psum -> invZ ----------------
__global__ __launch_bounds__(256) void k_comb(const float4* __restrict__ psum, float* __restrict__ hstat) {
    __shared__ float4 zred[4];
    int tid = threadIdx.x, lane = tid & 63, wid = tid >> 6;
    float4 z = {0.f, 0.f, 0.f, 0.f};
    for (int i = tid; i < NB_FILL; i += 256) {
        float4 s = psum[i];
        z.x += s.x; z.y += s.y; z.z += s.z; z.w += s.w;
    }
    #pragma unroll
    for (int m = 32; m > 0; m >>= 1) {
        z.x += __shfl_xor(z.x, m, 64);
        z.y += __shfl_xor(z.y, m, 64);
        z.z += __shfl_xor(z.z, m, 64);
        z.w += __shfl_xor(z.w, m, 64);
    }
    if (lane == 0) zred[wid] = z;
    __syncthreads();
    if (tid == 0) {
        float4 t;
        t.x = zred[0].x + zred[1].x + zred[2].x + zred[3].x;
        t.y = zred[0].y + zred[1].y + zred[2].y + zred[3].y;
        t.z = zred[0].z + zred[1].z + zred[2].z + zred[3].z;
        t.w = zred[0].w + zred[1].w + zred[2].w + zred[3].w;
        hstat[0] = 1.0f / t.x; hstat[1] = 1.0f / t.y;
        hstat[2] = 1.0f / t.z; hstat[3] = 1.0f / t.w;
    }
}

// ---------------- gather: out[n] = b + invZ*Ed[n] * sum_{j<cnt[n]} Es[s_j] * h16[s_j] ----------------
// one wave per dst node; u16 bucket; x16 unroll (avg deg ~17) for deep MLP
__global__ __launch_bounds__(256) void k_gather(const int* __restrict__ cnt,
                                                const unsigned short* __restrict__ bucket,
                                                const float* __restrict__ Es, const float* __restrict__ Ed,
                                                const _Float16* __restrict__ h16, const float* __restrict__ b,
                                                const float* __restrict__ hstat, float* __restrict__ out) {
    int n = blockIdx.x * 4 + (threadIdx.x >> 6);
    int lane = threadIdx.x & 63;
    int head = lane >> 4;
    int len = cnt[n]; len = len < CAP ? len : CAP;
    const unsigned short* bsi = bucket + n * CAP;
    const half4v* h4 = (const half4v*)h16;   // index: s*64 + lane
    float4 a0 = {0.f, 0.f, 0.f, 0.f}, a1 = a0, a2 = a0, a3 = a0;
    int j = 0;
    for (; j + 15 < len; j += 16) {
        int s[16];
        float w[16];
        #pragma unroll
        for (int q = 0; q < 16; ++q) s[q] = bsi[j + q];
        #pragma unroll
        for (int q = 0; q < 16; ++q) w[q] = Es[s[q] * 4 + head];
        half4v v[16];
        #pragma unroll
        for (int q = 0; q < 16; ++q) v[q] = h4[s[q] * 64 + lane];
        #pragma unroll
        for (int q = 0; q < 16; q += 4) {
            a0.x += w[q] * (float)v[q].x;     a0.y += w[q] * (float)v[q].y;
            a0.z += w[q] * (float)v[q].z;     a0.w += w[q] * (float)v[q].w;
            a1.x += w[q+1] * (float)v[q+1].x; a1.y += w[q+1] * (float)v[q+1].y;
            a1.z += w[q+1] * (float)v[q+1].z; a1.w += w[q+1] * (float)v[q+1].w;
            a2.x += w[q+2] * (float)v[q+2].x; a2.y += w[q+2] * (float)v[q+2].y;
            a2.z += w[q+2] * (float)v[q+2].z; a2.w += w[q+2] * (float)v[q+2].w;
            a3.x += w[q+3] * (float)v[q+3].x; a3.y += w[q+3] * (float)v[q+3].y;
            a3.z += w[q+3] * (float)v[q+3].z; a3.w += w[q+3] * (float)v[q+3].w;
        }
    }
    for (; j + 7 < len; j += 8) {
        int s0 = bsi[j],     s1 = bsi[j + 1], s2 = bsi[j + 2], s3 = bsi[j + 3];
        int s4 = bsi[j + 4], s5 = bsi[j + 5], s6 = bsi[j + 6], s7 = bsi[j + 7];
        float w0 = Es[s0 * 4 + head], w1 = Es[s1 * 4 + head];
        float w2 = Es[s2 * 4 + head], w3 = Es[s3 * 4 + head];
        float w4 = Es[s4 * 4 + head], w5 = Es[s5 * 4 + head];
        float w6 = Es[s6 * 4 + head], w7 = Es[s7 * 4 + head];
        half4v v0 = h4[s0 * 64 + lane], v1 = h4[s1 * 64 + lane];
        half4v v2 = h4[s2 * 64 + lane], v3 = h4[s3 * 64 + lane];
        half4v v4 = h4[s4 * 64 + lane], v5 = h4[s5 * 64 + lane];
        half4v v6 = h4[s6 * 64 + lane], v7 = h4[s7 * 64 + lane];
        a0.x += w0 * (float)v0.x; a0.y += w0 * (float)v0.y; a0.z += w0 * (float)v0.z; a0.w += w0 * (float)v0.w;
        a1.x += w1 * (float)v1.x; a1.y += w1 * (float)v1.y; a1.z += w1 * (float)v1.z; a1.w += w1 * (float)v1.w;
        a2.x += w2 * (float)v2.x; a2.y += w2 * (float)v2.y; a2.z += w2 * (float)v2.z; a2.w += w2 * (float)v2.w;
        a3.x += w3 * (float)v3.x; a3.y += w3 * (float)v3.y; a3.z += w3 * (float)v3.z; a3.w += w3 * (float)v3.w;
        a0.x += w4 * (float)v4.x; a0.y += w4 * (float)v4.y; a0.z += w4 * (float)v4.z; a0.w += w4 * (float)v4.w;
        a1.x += w5 * (float)v5.x; a1.y += w5 * (float)v5.y; a1.z += w5 * (float)v5.z; a1.w += w5 * (float)v5.w;
        a2.x += w6 * (float)v6.x; a2.y += w6 * (float)v6.y; a2.z += w6 * (float)v6.z; a2.w += w6 * (float)v6.w;
        a3.x += w7 * (float)v7.x; a3.y += w7 * (float)v7.y; a3.z += w7 * (float)v7.z; a3.w += w7 * (float)v7.w;
    }
    for (; j + 3 < len; j += 4) {
        int s0 = bsi[j], s1 = bsi[j + 1], s2 = bsi[j + 2], s3 = bsi[j + 3];
        float w0 = Es[s0 * 4 + head], w1 = Es[s1 * 4 + head];
        float w2 = Es[s2 * 4 + head], w3 = Es[s3 * 4 + head];
        half4v v0 = h4[s0 * 64 + lane], v1 = h4[s1 * 64 + lane];
        half4v v2 = h4[s2 * 64 + lane], v3 = h4[s3 * 64 + lane];
        a0.x += w0 * (float)v0.x; a0.y += w0 * (float)v0.y; a0.z += w0 * (float)v0.z; a0.w += w0 * (float)v0.w;
        a1.x += w1 * (float)v1.x; a1.y += w1 * (float)v1.y; a1.z += w1 * (float)v1.z; a1.w += w1 * (float)v1.w;
        a2.x += w2 * (float)v2.x; a2.y += w2 * (float)v2.y; a2.z += w2 * (float)v2.z; a2.w += w2 * (float)v2.w;
        a3.x += w3 * (float)v3.x; a3.y += w3 * (float)v3.y; a3.z += w3 * (float)v3.z; a3.w += w3 * (float)v3.w;
    }
    for (; j < len; ++j) {
        int s = bsi[j];
        float w = Es[s * 4 + head];
        half4v hv = h4[s * 64 + lane];
        a0.x += w * (float)hv.x; a0.y += w * (float)hv.y; a0.z += w * (float)hv.z; a0.w += w * (float)hv.w;
    }
    float scale = hstat[head] * Ed[n * 4 + head];
    float4 bb = ((const float4*)b)[lane];
    float4 o;
    o.x = bb.x + scale * (a0.x + a1.x + a2.x + a3.x);
    o.y = bb.y + scale * (a0.y + a1.y + a2.y + a3.y);
    o.z = bb.z + scale * (a0.z + a1.z + a2.z + a3.z);
    o.w = bb.w + scale * (a0.w + a1.w + a2.w + a3.w);
    ((float4*)out)[n * 64 + lane] = o;
}

extern "C" void kernel_launch(void* const* d_in, const int* in_sizes, int n_in,
                              void* d_out, int out_size, void* d_ws, size_t ws_size,
                              hipStream_t stream) {
    const float* x   = (const float*)d_in[0];
    const float* W   = (const float*)d_in[1];
    const float* att = (const float*)d_in[2];
    const float* b   = (const float*)d_in[3];
    const int*  eidx = (const int*)d_in[4];
    const int* es = eidx;        // edge_index[0] : sources
    const int* ed = eidx + EE;   // edge_index[1] : destinations
    float* out = (float*)d_out;

    float* ws = (float*)d_ws;
    _Float16* h16 = (_Float16*)ws;                     // 5,120,000 fp16 = 10.24 MB
    float* Es     = (float*)(h16 + NN * 256);          // 80,000 f (exp tables)
    float* Ed     = Es + NN * 4;                       // 80,000 f
    int*   cnt    = (int*)(Ed + NN * 4);               // 20,000 i (bin counters/cursors)
    unsigned short* bucket = (unsigned short*)(cnt + NN);  // 20,000*96 u16 = 3.84 MB
    float4* psum  = (float4*)(bucket + NN * CAP);      // NB_FILL f4
    float* hstat  = (float*)(psum + NB_FILL + 1);      // 4 f (invZ)
    _Float16* Wh  = (_Float16*)(hstat + 12);           // 65,536 fp16 (hi split, k-blocked)
    _Float16* Wl  = Wh + 256 * 256;                    // 65,536 fp16 (lo split, k-blocked)

    k_wsplit<<<256, 256, 0, stream>>>(W, Wh, Wl, cnt);
    k_gemm  <<<NB_GEMM, 256, 0, stream>>>(x, Wh, Wl, att, h16, Es, Ed);
    k_fill  <<<NB_FILL, 256, 0, stream>>>(es, ed, Es, Ed, cnt, bucket, psum);
    k_comb  <<<1, 256, 0, stream>>>(psum, hstat);
    k_gather<<<NN / 4, 256, 0, stream>>>(cnt, bucket, Es, Ed, h16, b, hstat, out);
}